// Round 1
// 930.863 us; speedup vs baseline: 1.5073x; 1.5073x over previous
//
#include <hip/hip_runtime.h>
#include <hip/hip_fp16.h>
#include <math.h>

#define N_NODES 500000
#define N_EDGES 4000000
#define FDIM 10   // IN_DIM + HID
#define HID 8

// Dest space: interleaved, dest = 2*col (mi side) or 2*row+1 (mo side).
#define DSPACE (2 * N_NODES)
#define NB 512
#define BSHIFT 11
#define BMASK 2047
#define NB_USED ((DSPACE + BMASK) / 2048)   // 489

#define IN_BLOCKS ((N_NODES + 255) / 256)       // 1954
#define ROWS_PAD (IN_BLOCKS * 256)              // 500224
#define NODE_BLOCKS2 ((N_NODES + 127) / 128)    // 3907 (128 nodes/block, 2 dests/node)

// ---------------------------------------------------------------------------
// Fast transcendentals (hw exp2/rcp; error ~1e-6 vs threshold 1.35e-2)
// ---------------------------------------------------------------------------
__device__ __forceinline__ float fast_tanh(float x) {
    float e = __builtin_amdgcn_exp2f(x * 2.885390082f);  // exp(2x)
    return 1.0f - 2.0f * __builtin_amdgcn_rcpf(e + 1.0f);
}
__device__ __forceinline__ float fast_sigmoid(float x) {
    float e = __builtin_amdgcn_exp2f(-1.442695041f * x); // exp(-x)
    return __builtin_amdgcn_rcpf(1.0f + e);
}

// fp16 pack/unpack through float bit-carriers
__device__ __forceinline__ float2 h2f2(float bits) {
    union { float f; __half2 h; } u; u.f = bits;
    return __half22float2(u.h);
}
__device__ __forceinline__ float f2h2(float a, float b) {
    union { float f; __half2 h; } u; u.h = __floats2half2_rn(a, b);
    return u.f;
}

// H row (float4 of 8 fp16) + X carrier (1 float of 2 fp16) -> 10 floats
__device__ __forceinline__ void unpack10(float4 H, float X, float* o) {
    float2 p0 = h2f2(H.x), p1 = h2f2(H.y), p2 = h2f2(H.z), p3 = h2f2(H.w), p4 = h2f2(X);
    o[0] = p0.x; o[1] = p0.y; o[2] = p1.x; o[3] = p1.y; o[4] = p2.x;
    o[5] = p2.y; o[6] = p3.x; o[7] = p3.y; o[8] = p4.x; o[9] = p4.y;
}

// acc[0..7] += xk * [wa|wb]
__device__ __forceinline__ void fma8(float* a, float xk, float4 wa, float4 wb) {
    a[0] += xk * wa.x; a[1] += xk * wa.y; a[2] += xk * wa.z; a[3] += xk * wa.w;
    a[4] += xk * wb.x; a[5] += xk * wb.y; a[6] += xk * wb.z; a[7] += xk * wb.w;
}

// ---------------------------------------------------------------------------
// Input network: H table (fp16, 16 B rows) + static X table (fp16, 4 B rows).
// X never changes across iterations, so it is written once and stays L2-hot.
// ---------------------------------------------------------------------------
__global__ __launch_bounds__(256) void input_kernel(const float* __restrict__ x,
                                                    const float* __restrict__ win_w,
                                                    const float* __restrict__ win_b,
                                                    float4* __restrict__ xh,
                                                    float* __restrict__ xs) {
    int n = blockIdx.x * 256 + threadIdx.x;   // grid covers ROWS_PAD exactly
    float x0 = 0.f, x1 = 0.f;
    if (n < N_NODES) { x0 = x[2 * n]; x1 = x[2 * n + 1]; }
    float h[HID];
#pragma unroll
    for (int j = 0; j < HID; j++)
        h[j] = fast_tanh(x0 * win_w[j] + x1 * win_w[HID + j] + win_b[j]);
    xh[n] = make_float4(f2h2(h[0], h[1]), f2h2(h[2], h[3]),
                        f2h2(h[4], h[5]), f2h2(h[6], h[7]));
    xs[n] = f2h2(x0, x1);
}

// ---------------------------------------------------------------------------
// K0: bucket histogram, LDS-staged.
// ---------------------------------------------------------------------------
__global__ void bucket_hist_kernel(const int* __restrict__ row,
                                   const int* __restrict__ col,
                                   int* __restrict__ g_cnt) {
    __shared__ int s_cnt[NB];
    int tid = threadIdx.x;
    for (int i = tid; i < NB; i += 256) s_cnt[i] = 0;
    __syncthreads();
    int base = blockIdx.x * 4096;
#pragma unroll
    for (int k = 0; k < 16; k++) {
        int e = base + k * 256 + tid;
        if (e < N_EDGES) {
            int c = col[e], r = row[e];
            atomicAdd(&s_cnt[(2 * c) >> BSHIFT], 1);
            atomicAdd(&s_cnt[(2 * r + 1) >> BSHIFT], 1);
        }
    }
    __syncthreads();
    for (int i = tid; i < NB; i += 256) {
        int v = s_cnt[i];
        if (v) atomicAdd(&g_cnt[i], v);
    }
}

// ---------------------------------------------------------------------------
// K1: exclusive scan of bucket counts.
// ---------------------------------------------------------------------------
__global__ void bucket_scan_kernel(const int* __restrict__ g_cnt,
                                   int* __restrict__ bucket_base,
                                   int* __restrict__ bucket_cur) {
    __shared__ int s[NB];
    int t = threadIdx.x;
    int c = g_cnt[t];
    s[t] = c;
    __syncthreads();
    for (int off = 1; off < NB; off <<= 1) {
        int v = (t >= off) ? s[t - off] : 0;
        __syncthreads();
        s[t] += v;
        __syncthreads();
    }
    int ex = s[t] - c;
    bucket_base[t] = ex;
    bucket_cur[t] = ex;
    if (t == NB - 1) bucket_base[NB] = s[t];
}

// ---------------------------------------------------------------------------
// K2: binning into bucket-ordered staging (LDS), coalesced flush.
// ---------------------------------------------------------------------------
__global__ void bin_kernel(const int* __restrict__ row,
                           const int* __restrict__ col,
                           int* __restrict__ bucket_cur,
                           unsigned int* __restrict__ binned) {
    __shared__ int s_cnt[NB];
    __shared__ int s_start[NB];
    __shared__ int s_cur[NB];
    __shared__ int s_gbase[NB];
    __shared__ unsigned int s_items[8192];
    __shared__ unsigned short s_ibkt[8192];

    int tid = threadIdx.x;
    if (tid < NB) s_cnt[tid] = 0;
    __syncthreads();

    int base = blockIdx.x * 4096;
    int cc[4], rr[4];
#pragma unroll
    for (int k = 0; k < 4; k++) {
        int e = base + k * 1024 + tid;
        bool ok = (e < N_EDGES);
        cc[k] = ok ? col[e] : -1;
        rr[k] = ok ? row[e] : -1;
        if (ok) {
            atomicAdd(&s_cnt[(2 * cc[k]) >> BSHIFT], 1);
            atomicAdd(&s_cnt[(2 * rr[k] + 1) >> BSHIFT], 1);
        }
    }
    __syncthreads();

    if (tid < NB) s_start[tid] = s_cnt[tid];
    __syncthreads();
    for (int off = 1; off < NB; off <<= 1) {
        int v = 0;
        if (tid < NB && tid >= off) v = s_start[tid - off];
        __syncthreads();
        if (tid < NB) s_start[tid] += v;
        __syncthreads();
    }
    if (tid < NB) {
        int ex = s_start[tid] - s_cnt[tid];
        s_start[tid] = ex;
        s_cur[tid] = ex;
    }
    __syncthreads();

#pragma unroll
    for (int k = 0; k < 4; k++) {
        if (cc[k] >= 0) {
            int d0 = 2 * cc[k];
            int b0 = d0 >> BSHIFT;
            int s0 = atomicAdd(&s_cur[b0], 1);
            s_items[s0] = ((unsigned)(d0 & BMASK) << 19) | (unsigned)rr[k];
            s_ibkt[s0] = (unsigned short)b0;
            int d1 = 2 * rr[k] + 1;
            int b1 = d1 >> BSHIFT;
            int s1 = atomicAdd(&s_cur[b1], 1);
            s_items[s1] = ((unsigned)(d1 & BMASK) << 19) | (unsigned)cc[k];
            s_ibkt[s1] = (unsigned short)b1;
        }
    }
    __syncthreads();

    if (tid < NB) s_gbase[tid] = atomicAdd(&bucket_cur[tid], s_cnt[tid]);
    __syncthreads();

    int tot = s_start[NB - 1] + s_cnt[NB - 1];
    for (int s = tid; s < tot; s += 1024) {
        int b = s_ibkt[s];
        int g = s_gbase[b] + (s - s_start[b]);
        binned[g] = s_items[s];
    }
}

// ---------------------------------------------------------------------------
// K3: CSR finalize per bucket, all fine-grained work in LDS.
// ---------------------------------------------------------------------------
__global__ void csr_kernel(const unsigned int* __restrict__ binned,
                           const int* __restrict__ bucket_base,
                           int* __restrict__ offs,
                           int* __restrict__ entries) {
    __shared__ int s_deg[2048];
    __shared__ int s_cur[2048];
    __shared__ int s_pair[1024];

    int t = threadIdx.x;
    int b = blockIdx.x;
    if (b == 0 && t == 0) offs[DSPACE] = 2 * N_EDGES;

    int ebase = bucket_base[b];
    int eend = bucket_base[b + 1];

    s_deg[t] = 0;
    s_deg[t + 1024] = 0;
    __syncthreads();

    for (int p = ebase + t; p < eend; p += 1024)
        atomicAdd(&s_deg[binned[p] >> 19], 1);
    __syncthreads();

    int d0 = s_deg[2 * t], d1 = s_deg[2 * t + 1];
    s_pair[t] = d0 + d1;
    __syncthreads();
    for (int off = 1; off < 1024; off <<= 1) {
        int v = (t >= off) ? s_pair[t - off] : 0;
        __syncthreads();
        s_pair[t] += v;
        __syncthreads();
    }
    int pex = s_pair[t] - (d0 + d1);
    s_cur[2 * t] = pex;
    s_cur[2 * t + 1] = pex + d0;

    int dest0 = b * 2048 + 2 * t;
    if (dest0 < DSPACE) offs[dest0] = ebase + pex;
    if (dest0 + 1 < DSPACE) offs[dest0 + 1] = ebase + pex + d0;
    __syncthreads();

    for (int p = ebase + t; p < eend; p += 1024) {
        unsigned int it = binned[p];
        int dl = it >> 19;
        int other = it & 0x7FFFF;
        int pos = atomicAdd(&s_cur[dl], 1);
        entries[ebase + pos] = other;
    }
}

// ---------------------------------------------------------------------------
// Final edge network -> out  (split-table fp16 gathers, float4 weight reads)
// ---------------------------------------------------------------------------
__global__ __launch_bounds__(256) void edge_kernel(const int* __restrict__ row,
                                                   const int* __restrict__ col,
                                                   const float4* __restrict__ xh,
                                                   const float* __restrict__ xs,
                                                   const float* __restrict__ e1_w,
                                                   const float* __restrict__ e1_b,
                                                   const float* __restrict__ e2_w,
                                                   const float* __restrict__ e2_b,
                                                   float* __restrict__ out) {
    __shared__ float4 s_w4[40];     // e1_w [20][8], k-major, j contiguous
    __shared__ float s_b[HID];
    __shared__ float s_v[HID];
    __shared__ float s_c[1];
    int tid = threadIdx.x;
    float* wf = (float*)s_w4;
    if (tid < 160) wf[tid] = e1_w[tid];
    else if (tid < 168) s_b[tid - 160] = e1_b[tid - 160];
    else if (tid < 176) s_v[tid - 168] = e2_w[tid - 168];
    else if (tid == 176) s_c[0] = e2_b[0];
    __syncthreads();

    int i = blockIdx.x * 256 + tid;
    if (i >= N_EDGES) return;

    int r = row[i], c = col[i];
    float4 aH = xh[c]; float aX = xs[c];
    float4 bH = xh[r]; float bX = xs[r];
    float a[FDIM], bb[FDIM];
    unpack10(aH, aX, a);
    unpack10(bH, bX, bb);

    float acc[HID];
#pragma unroll
    for (int j = 0; j < HID; j++) acc[j] = s_b[j];
#pragma unroll
    for (int k = 0; k < FDIM; k++)
        fma8(acc, a[k], s_w4[2 * k], s_w4[2 * k + 1]);
#pragma unroll
    for (int k = 0; k < FDIM; k++)
        fma8(acc, bb[k], s_w4[20 + 2 * k], s_w4[21 + 2 * k]);

    float d = s_c[0];
#pragma unroll
    for (int j = 0; j < HID; j++) d += fast_tanh(acc[j]) * s_v[j];
    out[i] = fast_sigmoid(d);
}

// ---------------------------------------------------------------------------
// Fused edge+gather+node network.
//   256 threads / 128 nodes per block: tid<128 -> dest 2n (mi side),
//   tid>=128 -> dest 2n+1 (mo side). mo crosses via LDS for the node net.
//   H rows: one aligned dwordx4 gather; X: one dword from the 2 MB static
//   table (L2-resident). Next-neighbor row software-prefetched.
// ---------------------------------------------------------------------------
__global__ __launch_bounds__(256) void node_kernel(const float4* __restrict__ xh,
                                                   const float* __restrict__ xs,
                                                   const int* __restrict__ offs,
                                                   const int* __restrict__ entries,
                                                   const float* __restrict__ e1_w,
                                                   const float* __restrict__ e1_b,
                                                   const float* __restrict__ e2_w,
                                                   const float* __restrict__ e2_b,
                                                   const float* __restrict__ n1_w,
                                                   const float* __restrict__ n1_b,
                                                   const float* __restrict__ n2_w,
                                                   const float* __restrict__ n2_b,
                                                   float4* __restrict__ xh_next) {
    __shared__ float4 s_e1w4[40];   // [20][8] floats
    __shared__ float s_e1b[HID];
    __shared__ float s_e2w[HID];
    __shared__ float s_e2b[1];
    __shared__ float4 s_n1w4[60];   // [30][8] floats
    __shared__ float s_n1b[HID];
    __shared__ float4 s_n2w4[16];   // [8][8] floats
    __shared__ float s_n2b[HID];
    __shared__ float s_mo[128 * 11];  // stride 11 (coprime 32 -> no bank conflict)

    int tid = threadIdx.x;
    float* e1f = (float*)s_e1w4;
    if (tid < 160) e1f[tid] = e1_w[tid];
    else if (tid < 168) s_e1b[tid - 160] = e1_b[tid - 160];
    else if (tid < 176) s_e2w[tid - 168] = e2_w[tid - 168];
    else if (tid == 176) s_e2b[0] = e2_b[0];
    float* n1f = (float*)s_n1w4;
    if (tid < 240) n1f[tid] = n1_w[tid];
    else if (tid < 248) s_n1b[tid - 240] = n1_b[tid - 240];
    float* n2f = (float*)s_n2w4;
    if (tid < 64) n2f[tid] = n2_w[tid];
    else if (tid < 72) s_n2b[tid - 64] = n2_b[tid - 64];
    __syncthreads();

    bool up = tid >= 128;
    int lt = up ? tid - 128 : tid;
    int n = blockIdx.x * 128 + lt;
    bool act = n < N_NODES;

    // mi side (dest 2n): self = col half (rows 0..9), other = row half (10..19)
    // mo side (dest 2n+1): self = row half, other = col half
    int selfBase = up ? 20 : 0;
    int othBase  = up ? 0 : 20;
    int dest = 2 * n + (up ? 1 : 0);

    float e2w_r[HID];
#pragma unroll
    for (int j = 0; j < HID; j++) e2w_r[j] = s_e2w[j];
    float e2b_r = s_e2b[0];

    float xn[FDIM];
    float m[FDIM];
#pragma unroll
    for (int k = 0; k < FDIM; k++) m[k] = 0.f;

    if (act) {
        float4 hN = xh[n]; float xN = xs[n];
        unpack10(hN, xN, xn);

        // self-half dot (bias folded in)
        float us[HID];
#pragma unroll
        for (int j = 0; j < HID; j++) us[j] = s_e1b[j];
#pragma unroll
        for (int k = 0; k < FDIM; k++)
            fma8(us, xn[k], s_e1w4[selfBase + 2 * k], s_e1w4[selfBase + 2 * k + 1]);

        int p0 = offs[dest], p1 = offs[dest + 1];
        float4 cH = make_float4(0.f, 0.f, 0.f, 0.f); float cX = 0.f;
        if (p0 < p1) { int o = entries[p0]; cH = xh[o]; cX = xs[o]; }
        for (int p = p0; p < p1; ++p) {
            // prefetch next neighbor row before consuming current
            float4 nH = cH; float nX = cX;
            if (p + 1 < p1) { int o2 = entries[p + 1]; nH = xh[o2]; nX = xs[o2]; }

            float xo[FDIM];
            unpack10(cH, cX, xo);

            float acc[HID];
#pragma unroll
            for (int j = 0; j < HID; j++) acc[j] = us[j];
#pragma unroll
            for (int k = 0; k < FDIM; k++)
                fma8(acc, xo[k], s_e1w4[othBase + 2 * k], s_e1w4[othBase + 2 * k + 1]);

            float d = e2b_r;
#pragma unroll
            for (int j = 0; j < HID; j++) d += fast_tanh(acc[j]) * e2w_r[j];
            float e = fast_sigmoid(d);
#pragma unroll
            for (int k = 0; k < FDIM; k++) m[k] += e * xo[k];

            cH = nH; cX = nX;
        }
    }

    if (up && act) {
        int lb = lt * 11;
#pragma unroll
        for (int k = 0; k < FDIM; k++) s_mo[lb + k] = m[k];
    }
    __syncthreads();

    if (!up && act) {
        int lb = lt * 11;
        float h1[HID];
#pragma unroll
        for (int j = 0; j < HID; j++) h1[j] = s_n1b[j];
#pragma unroll
        for (int k = 0; k < FDIM; k++)                 // mi (in registers)
            fma8(h1, m[k], s_n1w4[2 * k], s_n1w4[2 * k + 1]);
#pragma unroll
        for (int k = 0; k < FDIM; k++)                 // mo (from partner via LDS)
            fma8(h1, s_mo[lb + k], s_n1w4[20 + 2 * k], s_n1w4[21 + 2 * k]);
#pragma unroll
        for (int k = 0; k < FDIM; k++)                 // xn (in registers)
            fma8(h1, xn[k], s_n1w4[40 + 2 * k], s_n1w4[41 + 2 * k]);
#pragma unroll
        for (int j = 0; j < HID; j++) h1[j] = fast_tanh(h1[j]);

        float H[HID];
#pragma unroll
        for (int j = 0; j < HID; j++) H[j] = s_n2b[j];
#pragma unroll
        for (int k = 0; k < HID; k++)
            fma8(H, h1[k], s_n2w4[2 * k], s_n2w4[2 * k + 1]);
#pragma unroll
        for (int j = 0; j < HID; j++) H[j] = fast_tanh(H[j]);

        xh_next[n] = make_float4(f2h2(H[0], H[1]), f2h2(H[2], H[3]),
                                 f2h2(H[4], H[5]), f2h2(H[6], H[7]));
    }
}

// ---------------------------------------------------------------------------
extern "C" void kernel_launch(void* const* d_in, const int* in_sizes, int n_in,
                              void* d_out, int out_size, void* d_ws, size_t ws_size,
                              hipStream_t stream) {
    const float* x      = (const float*)d_in[0];
    const int*   eidx   = (const int*)d_in[1];
    const float* win_w  = (const float*)d_in[2];
    const float* win_b  = (const float*)d_in[3];
    const float* e1_w   = (const float*)d_in[4];
    const float* e1_b   = (const float*)d_in[5];
    const float* e2_w   = (const float*)d_in[6];
    const float* e2_b   = (const float*)d_in[7];
    const float* n1_w   = (const float*)d_in[8];
    const float* n1_b   = (const float*)d_in[9];
    const float* n2_w   = (const float*)d_in[10];
    const float* n2_b   = (const float*)d_in[11];
    float* out = (float*)d_out;

    const int* row = eidx;
    const int* col = eidx + N_EDGES;

    // Workspace layout (~86 MB):
    float4* xh0 = (float4*)d_ws;                         // ROWS_PAD * 16 B = 8 MB
    float4* xh1 = xh0 + ROWS_PAD;                        // 8 MB
    float*  xs  = (float*)(xh1 + ROWS_PAD);              // ROWS_PAD * 4 B = 2 MB
    unsigned int* binned = (unsigned int*)(xs + ROWS_PAD); // 2E uints = 32 MB
    int* entries = (int*)(binned + 2 * (size_t)N_EDGES); // 2E = 32 MB
    int* offs        = entries + 2 * (size_t)N_EDGES;    // D+1 (+pad)
    int* g_cnt       = offs + DSPACE + 64;               // 512
    int* bucket_base = g_cnt + NB;                       // 513 (+pad)
    int* bucket_cur  = bucket_base + NB + 64;            // 512

    const int BLK = 256;
    int edge_blocks = (N_EDGES + BLK - 1) / BLK;
    int chunk_blocks = (N_EDGES + 4095) / 4096;

    // --- CSR build ---
    hipMemsetAsync(g_cnt, 0, NB * sizeof(int), stream);
    bucket_hist_kernel<<<chunk_blocks, 256, 0, stream>>>(row, col, g_cnt);
    bucket_scan_kernel<<<1, NB, 0, stream>>>(g_cnt, bucket_base, bucket_cur);
    bin_kernel<<<chunk_blocks, 1024, 0, stream>>>(row, col, bucket_cur, binned);
    csr_kernel<<<NB_USED, 1024, 0, stream>>>(binned, bucket_base, offs, entries);

    // --- input network ---
    input_kernel<<<IN_BLOCKS, BLK, 0, stream>>>(x, win_w, win_b, xh0, xs);

    // --- message-passing iterations (ping-pong H table only) ---
    float4* cur = xh0;
    float4* nxt = xh1;
    for (int it = 0; it < 3; it++) {
        node_kernel<<<NODE_BLOCKS2, BLK, 0, stream>>>(
            cur, xs, offs, entries, e1_w, e1_b, e2_w, e2_b,
            n1_w, n1_b, n2_w, n2_b, nxt);
        float4* t = cur; cur = nxt; nxt = t;
    }

    // --- final edge network -> out ---
    edge_kernel<<<edge_blocks, BLK, 0, stream>>>(
        row, col, cur, xs, e1_w, e1_b, e2_w, e2_b, out);
}